// Round 16
// baseline (244.189 us; speedup 1.0000x reference)
//
#include <hip/hip_runtime.h>
#include <hip/hip_bf16.h>

#define NN 50000
#define NE 600000
#define FD 128
#define NG 512
#define NC 10
static constexpr float EPS_BN = 1e-5f;

typedef __bf16 bf16x8 __attribute__((ext_vector_type(8)));
typedef float f32x4 __attribute__((ext_vector_type(4)));

__device__ __forceinline__ unsigned short f2bf(float x) {
  unsigned u = __float_as_uint(x);
  u = (u + 0x7FFFu + ((u >> 16) & 1u)) >> 16;
  return (unsigned short)u;
}
__device__ __forceinline__ float bf2f(unsigned short h) {
  return __uint_as_float(((unsigned)h) << 16);
}

// ---------------- zero deg + bn accumulators ----------------
__global__ __launch_bounds__(256) void k_zero(float4* __restrict__ p) {
  int i = blockIdx.x * 256 + threadIdx.x;
  if (i < 13536) p[i] = make_float4(0.f, 0.f, 0.f, 0.f);
}

// ---------------- degree: XCD-partitioned scatter ----------------
#define FILL_CHUNKS 293                       // 293*2048 >= 600000
#define GRID_E8 (8 * FILL_CHUNKS)             // 2344
#define DRANGE 6250
__global__ __launch_bounds__(256) void k_deg_scatter(const int* __restrict__ dst, float* __restrict__ deg) {
  int b = blockIdx.x, t = threadIdx.x;
  int g = b & 7;
  int chunk = b >> 3;
  int dlo = g * DRANGE, dhi = dlo + DRANGE;
  int e0 = chunk * 2048;
#pragma unroll
  for (int i = 0; i < 8; ++i) {
    int e = e0 + i * 256 + t;
    if (e < NE) {
      int d = dst[e];
      if (d >= dlo && d < dhi) unsafeAtomicAdd(&deg[d], 1.0f);
    }
  }
}

// ---------------- CSR build: multi-block exclusive scan of in-edge counts ----------------
#define NB 196   // ceil(50000/256)
__global__ __launch_bounds__(256) void k_bsum(const float* __restrict__ deg, int* __restrict__ bsum) {
  __shared__ int s[256];
  int t = threadIdx.x, i = blockIdx.x * 256 + t;
  s[t] = (i < NN) ? (int)deg[i] : 0;
  __syncthreads();
  for (int o = 128; o > 0; o >>= 1) { if (t < o) s[t] += s[t + o]; __syncthreads(); }
  if (t == 0) bsum[blockIdx.x] = s[0];
}

__global__ __launch_bounds__(256) void k_bscan(const int* __restrict__ bsum, int* __restrict__ bbase) {
  __shared__ int s[256];
  int t = threadIdx.x;
  int v = (t < NB) ? bsum[t] : 0;
  s[t] = v; __syncthreads();
  for (int o = 1; o < 256; o <<= 1) {
    int a = (t >= o) ? s[t - o] : 0; __syncthreads();
    s[t] += a; __syncthreads();
  }
  if (t < NB) bbase[t] = s[t] - v;
}

// ---------------- rowoff (+dinv) fused with weight-cvt (hi, pre-swizzled) and gstart ----------------
__global__ __launch_bounds__(256) void k_rowoff_cvt(float* __restrict__ deg, const int* __restrict__ bbase,
                                                    int* __restrict__ row_off, int* __restrict__ cursor,
                                                    const float* __restrict__ W1, const float* __restrict__ W2,
                                                    const float* __restrict__ W3, unsigned short* __restrict__ w2,
                                                    const int* __restrict__ batch, int* __restrict__ gstart) {
  int b = blockIdx.x, t = threadIdx.x;
  if (b < NB) {
    __shared__ int s[256];
    int i = b * 256 + t;
    float dv = (i < NN) ? deg[i] : 0.f;
    int c = (int)dv;
    s[t] = c; __syncthreads();
    for (int o = 1; o < 256; o <<= 1) {
      int a = (t >= o) ? s[t - o] : 0; __syncthreads();
      s[t] += a; __syncthreads();
    }
    int excl = s[t] - c + bbase[b];
    if (i <= NN) {
      row_off[i] = excl;
      if (i < NN) {
        cursor[i] = excl;
        deg[i] = rsqrtf(dv + 1.0f);
      }
    }
  } else if (b < NB + 48) {
    int bb = b - NB;
    int m = bb >> 4;
    const float* W = (m == 0) ? W1 : ((m == 1) ? W2 : W3);
    int i = (bb & 15) * 256 + t;
    float4 v = ((const float4*)W)[i];
    ushort4 hv;
    hv.x = f2bf(v.x); hv.y = f2bf(v.y); hv.z = f2bf(v.z); hv.w = f2bf(v.w);
    int e0 = i * 4, row = e0 >> 7, col = e0 & 127;
    int sc_ = ((col & 120) ^ ((row & 7) << 3)) | (col & 7);   // 16B-group XOR swizzle
    *(ushort4*)(w2 + m * FD * FD + row * FD + sc_) = hv;
  } else {
    int g = (b - NB - 48) * 256 + t;
    if (g > NG) return;
    int lo = 0, hi = NN;
    while (lo < hi) {
      int mid = (lo + hi) >> 1;
      if (batch[mid] < g) lo = mid + 1; else hi = mid;
    }
    gstart[g] = lo;
  }
}

// ---------------- CSR fill: XCD-partitioned ----------------
__global__ __launch_bounds__(256) void k_fill(const int* __restrict__ src, const int* __restrict__ dst,
                                              const float* __restrict__ dinv, int* __restrict__ cursor,
                                              int2* __restrict__ csr) {
  int b = blockIdx.x, t = threadIdx.x;
  int g = b & 7;
  int chunk = b >> 3;
  int dlo = g * DRANGE, dhi = dlo + DRANGE;
  int e0 = chunk * 2048;
#pragma unroll
  for (int i = 0; i < 8; ++i) {
    int e = e0 + i * 256 + t;
    if (e < NE) {
      int d = dst[e];
      if (d >= dlo && d < dhi) {
        int s = src[e];
        float nrm = dinv[s] * dinv[d];
        int pos = atomicAdd(&cursor[d], 1);
        csr[pos] = make_int2(s, __float_as_int(nrm));
      }
    }
  }
}

// ---------------- MFMA GEMM: W(bf16) LDS 32KB; A fp32 (layer1) or bf16; x split hi+lo ----------------
template <int BN, int F32IN>
__global__ __launch_bounds__(256) void k_gemm(const void* __restrict__ in, const float* __restrict__ bn8,
                                              const unsigned short* __restrict__ wsrc,
                                              unsigned short* __restrict__ hb) {
  __shared__ unsigned short w_lds[FD * FD];   // 32KB, pre-swizzled
  __shared__ float s_musc[2 * FD];
  int t = threadIdx.x;
  {
    const uint4* s4 = (const uint4*)wsrc;
    uint4* d4 = (uint4*)w_lds;
#pragma unroll
    for (int c = 0; c < 8; ++c) d4[c * 256 + t] = s4[c * 256 + t];
  }
  if constexpr (BN != 0) {
    if (t < FD) {
      float s = 0.f, q = 0.f;
#pragma unroll
      for (int c = 0; c < 8; ++c) { s += bn8[c * FD + t]; q += bn8[1024 + c * FD + t]; }
      float m = s * (1.0f / NN);
      float v = fmaxf(q * (1.0f / NN) - m * m, 0.f);
      s_musc[t] = m;
      s_musc[FD + t] = rsqrtf(v + EPS_BN);
    }
  }
  __syncthreads();

  int w = t >> 6, l = t & 63;
  int rt = blockIdx.x * 4 + w;
  if (rt >= NN / 16) return;
  int r = l & 15, g = l >> 4;
  int ko = g * 8;
  f32x4 acc[8];
#pragma unroll
  for (int ct = 0; ct < 8; ++ct) acc[ct] = (f32x4){0.f, 0.f, 0.f, 0.f};

#pragma unroll
  for (int kk = 0; kk < FD; kk += 32) {
    float a0[8];
    if constexpr (F32IN != 0) {
      const float* p0 = (const float*)in + (size_t)(rt * 16 + r) * FD + kk + ko;
      float4 x0 = *(const float4*)p0;
      float4 x1 = *(const float4*)(p0 + 4);
      a0[0] = x0.x; a0[1] = x0.y; a0[2] = x0.z; a0[3] = x0.w;
      a0[4] = x1.x; a0[5] = x1.y; a0[6] = x1.z; a0[7] = x1.w;
    } else {
      uint4 pv = *(const uint4*)((const unsigned short*)in + (size_t)(rt * 16 + r) * FD + kk + ko);
      a0[0] = __uint_as_float(pv.x << 16); a0[1] = __uint_as_float(pv.x & 0xffff0000u);
      a0[2] = __uint_as_float(pv.y << 16); a0[3] = __uint_as_float(pv.y & 0xffff0000u);
      a0[4] = __uint_as_float(pv.z << 16); a0[5] = __uint_as_float(pv.z & 0xffff0000u);
      a0[6] = __uint_as_float(pv.w << 16); a0[7] = __uint_as_float(pv.w & 0xffff0000u);
    }
    if constexpr (BN != 0) {
      const float* mp = s_musc + kk + ko;
      float4 m0 = *(const float4*)mp, m1 = *(const float4*)(mp + 4);
      float4 s0 = *(const float4*)(mp + FD), s1 = *(const float4*)(mp + FD + 4);
      float mu[8] = {m0.x, m0.y, m0.z, m0.w, m1.x, m1.y, m1.z, m1.w};
      float sc[8] = {s0.x, s0.y, s0.z, s0.w, s1.x, s1.y, s1.z, s1.w};
#pragma unroll
      for (int i = 0; i < 8; ++i)
        a0[i] = fmaxf((a0[i] - mu[i]) * sc[i], 0.f);
    }
    bf16x8 ah, al;
#pragma unroll
    for (int i = 0; i < 8; ++i) {
      __bf16 h0 = (__bf16)a0[i];
      ah[i] = h0; al[i] = (__bf16)(a0[i] - (float)h0);
    }
#pragma unroll
    for (int ct = 0; ct < 8; ++ct) {
      int row = ct * 16 + r;
      int idx = row * FD + ((kk + ko) ^ ((r & 7) << 3));
      bf16x8 bh = *(const bf16x8*)(w_lds + idx);
      acc[ct] = __builtin_amdgcn_mfma_f32_16x16x32_bf16(ah, bh, acc[ct], 0, 0, 0);
      acc[ct] = __builtin_amdgcn_mfma_f32_16x16x32_bf16(al, bh, acc[ct], 0, 0, 0);
    }
  }
  // C/D layout: col = lane&15 (=r), row = g*4 + reg
#pragma unroll
  for (int ct = 0; ct < 8; ++ct)
#pragma unroll
    for (int i = 0; i < 4; ++i)
      hb[(size_t)(rt * 16 + g * 4 + i) * FD + ct * 16 + r] = f2bf(acc[ct][i]);
}

// ---------------- aggregation: fp32 accumulate, bf16 in AND out ----------------
template <int STATS>
__global__ __launch_bounds__(256) void k_agg(const unsigned short* __restrict__ hb,
                                             const float* __restrict__ dinv,
                                             const float* __restrict__ bias, const int* __restrict__ row_off,
                                             const int2* __restrict__ csr, unsigned short* __restrict__ outb,
                                             float* __restrict__ bn8) {
  int t = threadIdx.x;
  int n = blockIdx.x * 16 + (t >> 4);
  int q = t & 15;
  const uint4* hb4 = (const uint4*)hb;
  float dv = dinv[n];
  float s2 = dv * dv;
  float4 acc0 = ((const float4*)bias)[q * 2];
  float4 acc1 = ((const float4*)bias)[q * 2 + 1];
  {
    uint4 pv = hb4[(size_t)n * 16 + q];
    acc0.x = fmaf(s2, __uint_as_float(pv.x << 16), acc0.x);
    acc0.y = fmaf(s2, __uint_as_float(pv.x & 0xffff0000u), acc0.y);
    acc0.z = fmaf(s2, __uint_as_float(pv.y << 16), acc0.z);
    acc0.w = fmaf(s2, __uint_as_float(pv.y & 0xffff0000u), acc0.w);
    acc1.x = fmaf(s2, __uint_as_float(pv.z << 16), acc1.x);
    acc1.y = fmaf(s2, __uint_as_float(pv.z & 0xffff0000u), acc1.y);
    acc1.z = fmaf(s2, __uint_as_float(pv.w << 16), acc1.z);
    acc1.w = fmaf(s2, __uint_as_float(pv.w & 0xffff0000u), acc1.w);
  }
  int lo = row_off[n], hi = row_off[n + 1];
  for (int j = lo; j < hi; ++j) {
    int2 e = csr[j];
    float w = __int_as_float(e.y);
    uint4 pv = hb4[(size_t)e.x * 16 + q];
    acc0.x = fmaf(w, __uint_as_float(pv.x << 16), acc0.x);
    acc0.y = fmaf(w, __uint_as_float(pv.x & 0xffff0000u), acc0.y);
    acc0.z = fmaf(w, __uint_as_float(pv.y << 16), acc0.z);
    acc0.w = fmaf(w, __uint_as_float(pv.y & 0xffff0000u), acc0.w);
    acc1.x = fmaf(w, __uint_as_float(pv.z << 16), acc1.x);
    acc1.y = fmaf(w, __uint_as_float(pv.z & 0xffff0000u), acc1.y);
    acc1.z = fmaf(w, __uint_as_float(pv.w << 16), acc1.z);
    acc1.w = fmaf(w, __uint_as_float(pv.w & 0xffff0000u), acc1.w);
  }
  {
    unsigned short o[8];
    o[0] = f2bf(acc0.x); o[1] = f2bf(acc0.y); o[2] = f2bf(acc0.z); o[3] = f2bf(acc0.w);
    o[4] = f2bf(acc1.x); o[5] = f2bf(acc1.y); o[6] = f2bf(acc1.z); o[7] = f2bf(acc1.w);
    *(uint4*)(outb + (size_t)n * FD + q * 8) = *(uint4*)o;
  }

  if constexpr (STATS != 0) {
    __shared__ float red_s[16][FD + 4], red_q[16][FD + 4];
    int slot = t >> 4, f = q * 8;
    red_s[slot][f + 0] = acc0.x; red_s[slot][f + 1] = acc0.y;
    red_s[slot][f + 2] = acc0.z; red_s[slot][f + 3] = acc0.w;
    red_s[slot][f + 4] = acc1.x; red_s[slot][f + 5] = acc1.y;
    red_s[slot][f + 6] = acc1.z; red_s[slot][f + 7] = acc1.w;
    red_q[slot][f + 0] = acc0.x * acc0.x; red_q[slot][f + 1] = acc0.y * acc0.y;
    red_q[slot][f + 2] = acc0.z * acc0.z; red_q[slot][f + 3] = acc0.w * acc0.w;
    red_q[slot][f + 4] = acc1.x * acc1.x; red_q[slot][f + 5] = acc1.y * acc1.y;
    red_q[slot][f + 6] = acc1.z * acc1.z; red_q[slot][f + 7] = acc1.w * acc1.w;
    __syncthreads();
    if (t < FD) {
      float s = 0.f, qq = 0.f;
#pragma unroll
      for (int m = 0; m < 16; ++m) { s += red_s[m][t]; qq += red_q[m][t]; }
      int c = (blockIdx.x & 7) * FD + t;
      unsafeAtomicAdd(&bn8[c], s);
      unsafeAtomicAdd(&bn8[1024 + c], qq);
    }
  }
}

// ---------------- fused pool/head (bf16 input) ----------------
__global__ __launch_bounds__(512) void k_poolfinal(const unsigned short* __restrict__ hbB,
                                                   const int* __restrict__ gstart,
                                                   const float* __restrict__ Wlin, const float* __restrict__ blin,
                                                   float* __restrict__ out) {
  __shared__ float ps[4][FD];
  __shared__ float pp[FD];
  int g = blockIdx.x, t = threadIdx.x;
  int part = t >> 7, f = t & 127;
  int lo = gstart[g], hi = gstart[g + 1];
  float s = 0.f;
  for (int n = lo + part; n < hi; n += 4) s += bf2f(hbB[(size_t)n * FD + f]);
  ps[part][f] = s;
  __syncthreads();
  if (t < FD) {
    float tot = ps[0][t] + ps[1][t] + ps[2][t] + ps[3][t];
    pp[t] = tot * (1.0f / fmaxf((float)(hi - lo), 1.0f));
  }
  __syncthreads();
  if (t < NC) {
    float a = blin[t];
    for (int k = 0; k < FD; ++k) a = fmaf(pp[k], Wlin[t * FD + k], a);
    out[g * NC + t] = a;
  }
}

// ---------------- launch ----------------
extern "C" void kernel_launch(void* const* d_in, const int* in_sizes, int n_in,
                              void* d_out, int out_size, void* d_ws, size_t ws_size,
                              hipStream_t stream) {
  const float* x    = (const float*)d_in[0];
  const int*   ei   = (const int*)d_in[1];
  const int*   batch= (const int*)d_in[2];
  const float* W1   = (const float*)d_in[3];
  const float* b1   = (const float*)d_in[4];
  const float* W2   = (const float*)d_in[5];
  const float* b2   = (const float*)d_in[6];
  const float* W3   = (const float*)d_in[7];
  const float* b3   = (const float*)d_in[8];
  const float* Wlin = (const float*)d_in[9];
  const float* blin = (const float*)d_in[10];
  float* out = (float*)d_out;
  float* ws  = (float*)d_ws;

  const int* srcI = ei;
  const int* dstI = ei + NE;

  float* deg    = ws;                       // 50048; count then dinv
  float* bnA    = ws + 50048;               // 2048 (sum8 | sq8)
  float* bnB    = bnA + 2048;               // 2048
  int2*  csr    = (int2*)(bnB + 2048);      // NE int2
  int*   row_off= (int*)(csr + NE);         // 50048
  int*   cursor = row_off + 50048;          // 50048
  int*   gstart = cursor + 50048;           // 1024
  int*   bsum   = gstart + 1024;            // 256
  int*   bbase  = bsum + 256;               // 256
  unsigned short* w2  = (unsigned short*)(bbase + 256);  // 3*16384, pre-swizzled hi
  unsigned short* hb  = w2 + 3 * FD * FD;   // NN*FD bf16 gemm output
  unsigned short* hbB = hb + NN * FD;       // NN*FD bf16 agg output

  dim3 B(256);
  const int gGemm = (NN / 16 + 3) / 4;   // 782 blocks, 1 rt/wave
  const int gAgg  = NN / 16;             // 3125

  k_zero<<<53, B, 0, stream>>>((float4*)ws);
  k_deg_scatter<<<GRID_E8, B, 0, stream>>>(dstI, deg);
  k_bsum<<<NB, B, 0, stream>>>(deg, bsum);
  k_bscan<<<1, B, 0, stream>>>(bsum, bbase);
  k_rowoff_cvt<<<NB + 48 + 3, B, 0, stream>>>(deg, bbase, row_off, cursor,
                                              W1, W2, W3, w2, batch, gstart);
  k_fill<<<GRID_E8, B, 0, stream>>>(srcI, dstI, deg, cursor, csr);

  // layer 1 (fp32 x input)
  k_gemm<0, 1><<<gGemm, B, 0, stream>>>(x, nullptr, w2, hb);
  k_agg<1><<<gAgg, B, 0, stream>>>(hb, deg, b1, row_off, csr, hbB, bnA);

  // layer 2 (bf16 A input; BN+ReLU+musc-reduce fused into GEMM)
  k_gemm<1, 0><<<gGemm, B, 0, stream>>>(hbB, bnA, w2 + FD * FD, hb);
  k_agg<1><<<gAgg, B, 0, stream>>>(hb, deg, b2, row_off, csr, hbB, bnB);

  // layer 3
  k_gemm<1, 0><<<gGemm, B, 0, stream>>>(hbB, bnB, w2 + 2 * FD * FD, hb);
  k_agg<0><<<gAgg, B, 0, stream>>>(hb, deg, b3, row_off, csr, hbB, nullptr);

  // pool + head
  k_poolfinal<<<NG, 512, 0, stream>>>(hbB, gstart, Wlin, blin, out);
}

// Round 17
// 238.205 us; speedup vs baseline: 1.0251x; 1.0251x over previous
//
#include <hip/hip_runtime.h>
#include <hip/hip_bf16.h>

#define NN 50000
#define NE 600000
#define FD 128
#define NG 512
#define NC 10
static constexpr float EPS_BN = 1e-5f;

typedef __bf16 bf16x8 __attribute__((ext_vector_type(8)));
typedef float f32x4 __attribute__((ext_vector_type(4)));

__device__ __forceinline__ unsigned short f2bf(float x) {
  unsigned u = __float_as_uint(x);
  u = (u + 0x7FFFu + ((u >> 16) & 1u)) >> 16;
  return (unsigned short)u;
}
__device__ __forceinline__ float bf2f(unsigned short h) {
  return __uint_as_float(((unsigned)h) << 16);
}

// ---------------- zero deg + bn accumulators ----------------
__global__ __launch_bounds__(256) void k_zero(float4* __restrict__ p) {
  int i = blockIdx.x * 256 + threadIdx.x;
  if (i < 13536) p[i] = make_float4(0.f, 0.f, 0.f, 0.f);
}

// ---------------- degree: XCD-partitioned scatter ----------------
#define FILL_CHUNKS 293                       // 293*2048 >= 600000
#define GRID_E8 (8 * FILL_CHUNKS)             // 2344
#define DRANGE 6250
__global__ __launch_bounds__(256) void k_deg_scatter(const int* __restrict__ dst, float* __restrict__ deg) {
  int b = blockIdx.x, t = threadIdx.x;
  int g = b & 7;
  int chunk = b >> 3;
  int dlo = g * DRANGE, dhi = dlo + DRANGE;
  int e0 = chunk * 2048;
#pragma unroll
  for (int i = 0; i < 8; ++i) {
    int e = e0 + i * 256 + t;
    if (e < NE) {
      int d = dst[e];
      if (d >= dlo && d < dhi) unsafeAtomicAdd(&deg[d], 1.0f);
    }
  }
}

// ---------------- CSR build: multi-block exclusive scan of in-edge counts ----------------
#define NB 196   // ceil(50000/256)
__global__ __launch_bounds__(256) void k_bsum(const float* __restrict__ deg, int* __restrict__ bsum) {
  __shared__ int s[256];
  int t = threadIdx.x, i = blockIdx.x * 256 + t;
  s[t] = (i < NN) ? (int)deg[i] : 0;
  __syncthreads();
  for (int o = 128; o > 0; o >>= 1) { if (t < o) s[t] += s[t + o]; __syncthreads(); }
  if (t == 0) bsum[blockIdx.x] = s[0];
}

__global__ __launch_bounds__(256) void k_bscan(const int* __restrict__ bsum, int* __restrict__ bbase) {
  __shared__ int s[256];
  int t = threadIdx.x;
  int v = (t < NB) ? bsum[t] : 0;
  s[t] = v; __syncthreads();
  for (int o = 1; o < 256; o <<= 1) {
    int a = (t >= o) ? s[t - o] : 0; __syncthreads();
    s[t] += a; __syncthreads();
  }
  if (t < NB) bbase[t] = s[t] - v;
}

// ---------------- rowoff (+dinv) fused with weight-cvt (hi, pre-swizzled) and gstart ----------------
__global__ __launch_bounds__(256) void k_rowoff_cvt(float* __restrict__ deg, const int* __restrict__ bbase,
                                                    int* __restrict__ row_off, int* __restrict__ cursor,
                                                    const float* __restrict__ W1, const float* __restrict__ W2,
                                                    const float* __restrict__ W3, unsigned short* __restrict__ w2,
                                                    const int* __restrict__ batch, int* __restrict__ gstart) {
  int b = blockIdx.x, t = threadIdx.x;
  if (b < NB) {
    __shared__ int s[256];
    int i = b * 256 + t;
    float dv = (i < NN) ? deg[i] : 0.f;
    int c = (int)dv;
    s[t] = c; __syncthreads();
    for (int o = 1; o < 256; o <<= 1) {
      int a = (t >= o) ? s[t - o] : 0; __syncthreads();
      s[t] += a; __syncthreads();
    }
    int excl = s[t] - c + bbase[b];
    if (i <= NN) {
      row_off[i] = excl;
      if (i < NN) {
        cursor[i] = excl;
        deg[i] = rsqrtf(dv + 1.0f);
      }
    }
  } else if (b < NB + 48) {
    int bb = b - NB;
    int m = bb >> 4;
    const float* W = (m == 0) ? W1 : ((m == 1) ? W2 : W3);
    int i = (bb & 15) * 256 + t;
    float4 v = ((const float4*)W)[i];
    ushort4 hv;
    hv.x = f2bf(v.x); hv.y = f2bf(v.y); hv.z = f2bf(v.z); hv.w = f2bf(v.w);
    int e0 = i * 4, row = e0 >> 7, col = e0 & 127;
    int sc_ = ((col & 120) ^ ((row & 7) << 3)) | (col & 7);   // 16B-group XOR swizzle
    *(ushort4*)(w2 + m * FD * FD + row * FD + sc_) = hv;
  } else {
    int g = (b - NB - 48) * 256 + t;
    if (g > NG) return;
    int lo = 0, hi = NN;
    while (lo < hi) {
      int mid = (lo + hi) >> 1;
      if (batch[mid] < g) lo = mid + 1; else hi = mid;
    }
    gstart[g] = lo;
  }
}

// ---------------- CSR fill: XCD-partitioned, src only (no norm -- folded into hb) ----------------
__global__ __launch_bounds__(256) void k_fill(const int* __restrict__ src, const int* __restrict__ dst,
                                              int* __restrict__ cursor, int* __restrict__ csr_src) {
  int b = blockIdx.x, t = threadIdx.x;
  int g = b & 7;
  int chunk = b >> 3;
  int dlo = g * DRANGE, dhi = dlo + DRANGE;
  int e0 = chunk * 2048;
#pragma unroll
  for (int i = 0; i < 8; ++i) {
    int e = e0 + i * 256 + t;
    if (e < NE) {
      int d = dst[e];
      if (d >= dlo && d < dhi) {
        int pos = atomicAdd(&cursor[d], 1);
        csr_src[pos] = src[e];
      }
    }
  }
}

// ---------------- MFMA GEMM: writes hb' = dinv[row] * h[row] (bf16) ----------------
template <int BN, int F32IN>
__global__ __launch_bounds__(256) void k_gemm(const void* __restrict__ in, const float* __restrict__ bn8,
                                              const unsigned short* __restrict__ wsrc,
                                              const float* __restrict__ dinv,
                                              unsigned short* __restrict__ hb) {
  __shared__ unsigned short w_lds[FD * FD];   // 32KB, pre-swizzled
  __shared__ float s_musc[2 * FD];
  int t = threadIdx.x;
  {
    const uint4* s4 = (const uint4*)wsrc;
    uint4* d4 = (uint4*)w_lds;
#pragma unroll
    for (int c = 0; c < 8; ++c) d4[c * 256 + t] = s4[c * 256 + t];
  }
  if constexpr (BN != 0) {
    if (t < FD) {
      float s = 0.f, q = 0.f;
#pragma unroll
      for (int c = 0; c < 8; ++c) { s += bn8[c * FD + t]; q += bn8[1024 + c * FD + t]; }
      float m = s * (1.0f / NN);
      float v = fmaxf(q * (1.0f / NN) - m * m, 0.f);
      s_musc[t] = m;
      s_musc[FD + t] = rsqrtf(v + EPS_BN);
    }
  }
  __syncthreads();

  int w = t >> 6, l = t & 63;
  int rt = blockIdx.x * 4 + w;
  if (rt >= NN / 16) return;
  int r = l & 15, g = l >> 4;
  int ko = g * 8;
  f32x4 acc[8];
#pragma unroll
  for (int ct = 0; ct < 8; ++ct) acc[ct] = (f32x4){0.f, 0.f, 0.f, 0.f};

#pragma unroll
  for (int kk = 0; kk < FD; kk += 32) {
    float a0[8];
    if constexpr (F32IN != 0) {
      const float* p0 = (const float*)in + (size_t)(rt * 16 + r) * FD + kk + ko;
      float4 x0 = *(const float4*)p0;
      float4 x1 = *(const float4*)(p0 + 4);
      a0[0] = x0.x; a0[1] = x0.y; a0[2] = x0.z; a0[3] = x0.w;
      a0[4] = x1.x; a0[5] = x1.y; a0[6] = x1.z; a0[7] = x1.w;
    } else {
      uint4 pv = *(const uint4*)((const unsigned short*)in + (size_t)(rt * 16 + r) * FD + kk + ko);
      a0[0] = __uint_as_float(pv.x << 16); a0[1] = __uint_as_float(pv.x & 0xffff0000u);
      a0[2] = __uint_as_float(pv.y << 16); a0[3] = __uint_as_float(pv.y & 0xffff0000u);
      a0[4] = __uint_as_float(pv.z << 16); a0[5] = __uint_as_float(pv.z & 0xffff0000u);
      a0[6] = __uint_as_float(pv.w << 16); a0[7] = __uint_as_float(pv.w & 0xffff0000u);
    }
    if constexpr (BN != 0) {
      const float* mp = s_musc + kk + ko;
      float4 m0 = *(const float4*)mp, m1 = *(const float4*)(mp + 4);
      float4 s0 = *(const float4*)(mp + FD), s1 = *(const float4*)(mp + FD + 4);
      float mu[8] = {m0.x, m0.y, m0.z, m0.w, m1.x, m1.y, m1.z, m1.w};
      float sc[8] = {s0.x, s0.y, s0.z, s0.w, s1.x, s1.y, s1.z, s1.w};
#pragma unroll
      for (int i = 0; i < 8; ++i)
        a0[i] = fmaxf((a0[i] - mu[i]) * sc[i], 0.f);
    }
    bf16x8 ah, al;
#pragma unroll
    for (int i = 0; i < 8; ++i) {
      __bf16 h0 = (__bf16)a0[i];
      ah[i] = h0; al[i] = (__bf16)(a0[i] - (float)h0);
    }
#pragma unroll
    for (int ct = 0; ct < 8; ++ct) {
      int row = ct * 16 + r;
      int idx = row * FD + ((kk + ko) ^ ((r & 7) << 3));
      bf16x8 bh = *(const bf16x8*)(w_lds + idx);
      acc[ct] = __builtin_amdgcn_mfma_f32_16x16x32_bf16(ah, bh, acc[ct], 0, 0, 0);
      acc[ct] = __builtin_amdgcn_mfma_f32_16x16x32_bf16(al, bh, acc[ct], 0, 0, 0);
    }
  }
  // C/D layout: col = lane&15 (=r), row_in_tile = g*4 + i
  float dvr[4];
#pragma unroll
  for (int i = 0; i < 4; ++i) dvr[i] = dinv[rt * 16 + g * 4 + i];
#pragma unroll
  for (int ct = 0; ct < 8; ++ct)
#pragma unroll
    for (int i = 0; i < 4; ++i)
      hb[(size_t)(rt * 16 + g * 4 + i) * FD + ct * 16 + r] = f2bf(dvr[i] * acc[ct][i]);
}

// ---------------- aggregation: unweighted sum of hb' rows, then out = bias + dinv[n]*sum ----------------
template <int STATS>
__global__ __launch_bounds__(256) void k_agg(const unsigned short* __restrict__ hb,
                                             const float* __restrict__ dinv,
                                             const float* __restrict__ bias, const int* __restrict__ row_off,
                                             const int* __restrict__ csr_src, unsigned short* __restrict__ outb,
                                             float* __restrict__ bn8) {
  int t = threadIdx.x;
  int n = blockIdx.x * 16 + (t >> 4);
  int q = t & 15;
  const uint4* hb4 = (const uint4*)hb;
  float4 acc0, acc1;
  {
    uint4 pv = hb4[(size_t)n * 16 + q];    // self-loop term hb'[n]
    acc0.x = __uint_as_float(pv.x << 16); acc0.y = __uint_as_float(pv.x & 0xffff0000u);
    acc0.z = __uint_as_float(pv.y << 16); acc0.w = __uint_as_float(pv.y & 0xffff0000u);
    acc1.x = __uint_as_float(pv.z << 16); acc1.y = __uint_as_float(pv.z & 0xffff0000u);
    acc1.z = __uint_as_float(pv.w << 16); acc1.w = __uint_as_float(pv.w & 0xffff0000u);
  }
  int lo = row_off[n], hi = row_off[n + 1];
  for (int j = lo; j < hi; ++j) {
    int s = csr_src[j];
    uint4 pv = hb4[(size_t)s * 16 + q];
    acc0.x += __uint_as_float(pv.x << 16); acc0.y += __uint_as_float(pv.x & 0xffff0000u);
    acc0.z += __uint_as_float(pv.y << 16); acc0.w += __uint_as_float(pv.y & 0xffff0000u);
    acc1.x += __uint_as_float(pv.z << 16); acc1.y += __uint_as_float(pv.z & 0xffff0000u);
    acc1.z += __uint_as_float(pv.w << 16); acc1.w += __uint_as_float(pv.w & 0xffff0000u);
  }
  float dv = dinv[n];
  float4 b0 = ((const float4*)bias)[q * 2];
  float4 b1v = ((const float4*)bias)[q * 2 + 1];
  float4 o0, o1;
  o0.x = fmaf(dv, acc0.x, b0.x); o0.y = fmaf(dv, acc0.y, b0.y);
  o0.z = fmaf(dv, acc0.z, b0.z); o0.w = fmaf(dv, acc0.w, b0.w);
  o1.x = fmaf(dv, acc1.x, b1v.x); o1.y = fmaf(dv, acc1.y, b1v.y);
  o1.z = fmaf(dv, acc1.z, b1v.z); o1.w = fmaf(dv, acc1.w, b1v.w);
  {
    unsigned short o[8];
    o[0] = f2bf(o0.x); o[1] = f2bf(o0.y); o[2] = f2bf(o0.z); o[3] = f2bf(o0.w);
    o[4] = f2bf(o1.x); o[5] = f2bf(o1.y); o[6] = f2bf(o1.z); o[7] = f2bf(o1.w);
    *(uint4*)(outb + (size_t)n * FD + q * 8) = *(uint4*)o;
  }

  if constexpr (STATS != 0) {
    __shared__ float red_s[16][FD + 4], red_q[16][FD + 4];
    int slot = t >> 4, f = q * 8;
    red_s[slot][f + 0] = o0.x; red_s[slot][f + 1] = o0.y;
    red_s[slot][f + 2] = o0.z; red_s[slot][f + 3] = o0.w;
    red_s[slot][f + 4] = o1.x; red_s[slot][f + 5] = o1.y;
    red_s[slot][f + 6] = o1.z; red_s[slot][f + 7] = o1.w;
    red_q[slot][f + 0] = o0.x * o0.x; red_q[slot][f + 1] = o0.y * o0.y;
    red_q[slot][f + 2] = o0.z * o0.z; red_q[slot][f + 3] = o0.w * o0.w;
    red_q[slot][f + 4] = o1.x * o1.x; red_q[slot][f + 5] = o1.y * o1.y;
    red_q[slot][f + 6] = o1.z * o1.z; red_q[slot][f + 7] = o1.w * o1.w;
    __syncthreads();
    if (t < FD) {
      float s = 0.f, qq = 0.f;
#pragma unroll
      for (int m = 0; m < 16; ++m) { s += red_s[m][t]; qq += red_q[m][t]; }
      int c = (blockIdx.x & 7) * FD + t;
      unsafeAtomicAdd(&bn8[c], s);
      unsafeAtomicAdd(&bn8[1024 + c], qq);
    }
  }
}

// ---------------- fused pool/head (bf16 input) ----------------
__global__ __launch_bounds__(512) void k_poolfinal(const unsigned short* __restrict__ hbB,
                                                   const int* __restrict__ gstart,
                                                   const float* __restrict__ Wlin, const float* __restrict__ blin,
                                                   float* __restrict__ out) {
  __shared__ float ps[4][FD];
  __shared__ float pp[FD];
  int g = blockIdx.x, t = threadIdx.x;
  int part = t >> 7, f = t & 127;
  int lo = gstart[g], hi = gstart[g + 1];
  float s = 0.f;
  for (int n = lo + part; n < hi; n += 4) s += bf2f(hbB[(size_t)n * FD + f]);
  ps[part][f] = s;
  __syncthreads();
  if (t < FD) {
    float tot = ps[0][t] + ps[1][t] + ps[2][t] + ps[3][t];
    pp[t] = tot * (1.0f / fmaxf((float)(hi - lo), 1.0f));
  }
  __syncthreads();
  if (t < NC) {
    float a = blin[t];
    for (int k = 0; k < FD; ++k) a = fmaf(pp[k], Wlin[t * FD + k], a);
    out[g * NC + t] = a;
  }
}

// ---------------- launch ----------------
extern "C" void kernel_launch(void* const* d_in, const int* in_sizes, int n_in,
                              void* d_out, int out_size, void* d_ws, size_t ws_size,
                              hipStream_t stream) {
  const float* x    = (const float*)d_in[0];
  const int*   ei   = (const int*)d_in[1];
  const int*   batch= (const int*)d_in[2];
  const float* W1   = (const float*)d_in[3];
  const float* b1   = (const float*)d_in[4];
  const float* W2   = (const float*)d_in[5];
  const float* b2   = (const float*)d_in[6];
  const float* W3   = (const float*)d_in[7];
  const float* b3   = (const float*)d_in[8];
  const float* Wlin = (const float*)d_in[9];
  const float* blin = (const float*)d_in[10];
  float* out = (float*)d_out;
  float* ws  = (float*)d_ws;

  const int* srcI = ei;
  const int* dstI = ei + NE;

  float* deg    = ws;                       // 50048; count then dinv
  float* bnA    = ws + 50048;               // 2048 (sum8 | sq8)
  float* bnB    = bnA + 2048;               // 2048
  int*   csr_src= (int*)(bnB + 2048);       // NE
  int*   row_off= csr_src + NE;             // 50048
  int*   cursor = row_off + 50048;          // 50048
  int*   gstart = cursor + 50048;           // 1024
  int*   bsum   = gstart + 1024;            // 256
  int*   bbase  = bsum + 256;               // 256
  unsigned short* w2  = (unsigned short*)(bbase + 256);  // 3*16384, pre-swizzled hi
  unsigned short* hb  = w2 + 3 * FD * FD;   // NN*FD bf16 gemm output (dinv-scaled)
  unsigned short* hbB = hb + NN * FD;       // NN*FD bf16 agg output

  dim3 B(256);
  const int gGemm = (NN / 16 + 3) / 4;   // 782 blocks, 1 rt/wave
  const int gAgg  = NN / 16;             // 3125

  k_zero<<<53, B, 0, stream>>>((float4*)ws);
  k_deg_scatter<<<GRID_E8, B, 0, stream>>>(dstI, deg);
  k_bsum<<<NB, B, 0, stream>>>(deg, bsum);
  k_bscan<<<1, B, 0, stream>>>(bsum, bbase);
  k_rowoff_cvt<<<NB + 48 + 3, B, 0, stream>>>(deg, bbase, row_off, cursor,
                                              W1, W2, W3, w2, batch, gstart);
  k_fill<<<GRID_E8, B, 0, stream>>>(srcI, dstI, cursor, csr_src);

  // layer 1 (fp32 x input)
  k_gemm<0, 1><<<gGemm, B, 0, stream>>>(x, nullptr, w2, deg, hb);
  k_agg<1><<<gAgg, B, 0, stream>>>(hb, deg, b1, row_off, csr_src, hbB, bnA);

  // layer 2 (bf16 A input; BN+ReLU+musc-reduce fused into GEMM)
  k_gemm<1, 0><<<gGemm, B, 0, stream>>>(hbB, bnA, w2 + FD * FD, deg, hb);
  k_agg<1><<<gAgg, B, 0, stream>>>(hb, deg, b2, row_off, csr_src, hbB, bnB);

  // layer 3
  k_gemm<1, 0><<<gGemm, B, 0, stream>>>(hbB, bnB, w2 + 2 * FD * FD, deg, hb);
  k_agg<0><<<gAgg, B, 0, stream>>>(hb, deg, b3, row_off, csr_src, hbB, nullptr);

  // pool + head
  k_poolfinal<<<NG, 512, 0, stream>>>(hbB, gstart, Wlin, blin, out);
}

// Round 18
// 233.719 us; speedup vs baseline: 1.0448x; 1.0192x over previous
//
#include <hip/hip_runtime.h>
#include <hip/hip_bf16.h>

#define NN 50000
#define NE 600000
#define FD 128
#define NG 512
#define NC 10
static constexpr float EPS_BN = 1e-5f;

typedef __bf16 bf16x8 __attribute__((ext_vector_type(8)));
typedef float f32x4 __attribute__((ext_vector_type(4)));

__device__ __forceinline__ unsigned short f2bf(float x) {
  unsigned u = __float_as_uint(x);
  u = (u + 0x7FFFu + ((u >> 16) & 1u)) >> 16;
  return (unsigned short)u;
}
__device__ __forceinline__ float bf2f(unsigned short h) {
  return __uint_as_float(((unsigned)h) << 16);
}

// ---------------- zero deg + bn accumulators ----------------
__global__ __launch_bounds__(256) void k_zero(float4* __restrict__ p) {
  int i = blockIdx.x * 256 + threadIdx.x;
  if (i < 13536) p[i] = make_float4(0.f, 0.f, 0.f, 0.f);
}

// ---------------- degree: XCD-partitioned scatter ----------------
#define FILL_CHUNKS 293                       // 293*2048 >= 600000
#define GRID_E8 (8 * FILL_CHUNKS)             // 2344
#define DRANGE 6250
__global__ __launch_bounds__(256) void k_deg_scatter(const int* __restrict__ dst, float* __restrict__ deg) {
  int b = blockIdx.x, t = threadIdx.x;
  int g = b & 7;
  int chunk = b >> 3;
  int dlo = g * DRANGE, dhi = dlo + DRANGE;
  int e0 = chunk * 2048;
#pragma unroll
  for (int i = 0; i < 8; ++i) {
    int e = e0 + i * 256 + t;
    if (e < NE) {
      int d = dst[e];
      if (d >= dlo && d < dhi) unsafeAtomicAdd(&deg[d], 1.0f);
    }
  }
}

// ---------------- per-block sums of in-edge counts ----------------
#define NB 196   // ceil(50000/256)
__global__ __launch_bounds__(256) void k_bsum(const float* __restrict__ deg, int* __restrict__ bsum) {
  __shared__ int s[256];
  int t = threadIdx.x, i = blockIdx.x * 256 + t;
  s[t] = (i < NN) ? (int)deg[i] : 0;
  __syncthreads();
  for (int o = 128; o > 0; o >>= 1) { if (t < o) s[t] += s[t + o]; __syncthreads(); }
  if (t == 0) bsum[blockIdx.x] = s[0];
}

// ---------------- rowoff (+dinv, self-scanned bbase) fused with weight-cvt and gstart ----------------
__global__ __launch_bounds__(256) void k_rowoff_cvt(float* __restrict__ deg, const int* __restrict__ bsum,
                                                    int* __restrict__ row_off, int* __restrict__ cursor,
                                                    const float* __restrict__ W1, const float* __restrict__ W2,
                                                    const float* __restrict__ W3, unsigned short* __restrict__ w2,
                                                    const int* __restrict__ batch, int* __restrict__ gstart) {
  int b = blockIdx.x, t = threadIdx.x;
  if (b < NB) {
    __shared__ int s[256];
    __shared__ int base_s;
    // lane-parallel sum of bsum[0..b) via wave reduction in thread 0's wave
    if (t < 64) {
      int acc = 0;
      for (int i = t; i < b; i += 64) acc += bsum[i];
#pragma unroll
      for (int o = 32; o > 0; o >>= 1) acc += __shfl_down(acc, o, 64);
      if (t == 0) base_s = acc;
    }
    int i = b * 256 + t;
    float dv = (i < NN) ? deg[i] : 0.f;
    int c = (int)dv;
    s[t] = c; __syncthreads();
    for (int o = 1; o < 256; o <<= 1) {
      int a = (t >= o) ? s[t - o] : 0; __syncthreads();
      s[t] += a; __syncthreads();
    }
    int excl = s[t] - c + base_s;
    if (i <= NN) {
      row_off[i] = excl;
      if (i < NN) {
        cursor[i] = excl;
        deg[i] = rsqrtf(dv + 1.0f);
      }
    }
  } else if (b < NB + 48) {
    int bb = b - NB;
    int m = bb >> 4;
    const float* W = (m == 0) ? W1 : ((m == 1) ? W2 : W3);
    int i = (bb & 15) * 256 + t;
    float4 v = ((const float4*)W)[i];
    ushort4 hv;
    hv.x = f2bf(v.x); hv.y = f2bf(v.y); hv.z = f2bf(v.z); hv.w = f2bf(v.w);
    int e0 = i * 4, row = e0 >> 7, col = e0 & 127;
    int sc_ = ((col & 120) ^ ((row & 7) << 3)) | (col & 7);   // 16B-group XOR swizzle
    *(ushort4*)(w2 + m * FD * FD + row * FD + sc_) = hv;
  } else {
    int g = (b - NB - 48) * 256 + t;
    if (g > NG) return;
    int lo = 0, hi = NN;
    while (lo < hi) {
      int mid = (lo + hi) >> 1;
      if (batch[mid] < g) lo = mid + 1; else hi = mid;
    }
    gstart[g] = lo;
  }
}

// ---------------- CSR fill: XCD-partitioned, src only ----------------
__global__ __launch_bounds__(256) void k_fill(const int* __restrict__ src, const int* __restrict__ dst,
                                              int* __restrict__ cursor, int* __restrict__ csr_src) {
  int b = blockIdx.x, t = threadIdx.x;
  int g = b & 7;
  int chunk = b >> 3;
  int dlo = g * DRANGE, dhi = dlo + DRANGE;
  int e0 = chunk * 2048;
#pragma unroll
  for (int i = 0; i < 8; ++i) {
    int e = e0 + i * 256 + t;
    if (e < NE) {
      int d = dst[e];
      if (d >= dlo && d < dhi) {
        int pos = atomicAdd(&cursor[d], 1);
        csr_src[pos] = src[e];
      }
    }
  }
}

// ---------------- MFMA GEMM: writes hb' = dinv[row] * h[row] (bf16) ----------------
template <int BN, int F32IN>
__global__ __launch_bounds__(256) void k_gemm(const void* __restrict__ in, const float* __restrict__ bn8,
                                              const unsigned short* __restrict__ wsrc,
                                              const float* __restrict__ dinv,
                                              unsigned short* __restrict__ hb) {
  __shared__ unsigned short w_lds[FD * FD];   // 32KB, pre-swizzled
  __shared__ float s_musc[2 * FD];
  int t = threadIdx.x;
  {
    const uint4* s4 = (const uint4*)wsrc;
    uint4* d4 = (uint4*)w_lds;
#pragma unroll
    for (int c = 0; c < 8; ++c) d4[c * 256 + t] = s4[c * 256 + t];
  }
  if constexpr (BN != 0) {
    if (t < FD) {
      float s = 0.f, q = 0.f;
#pragma unroll
      for (int c = 0; c < 8; ++c) { s += bn8[c * FD + t]; q += bn8[1024 + c * FD + t]; }
      float m = s * (1.0f / NN);
      float v = fmaxf(q * (1.0f / NN) - m * m, 0.f);
      s_musc[t] = m;
      s_musc[FD + t] = rsqrtf(v + EPS_BN);
    }
  }
  __syncthreads();

  int w = t >> 6, l = t & 63;
  int rt = blockIdx.x * 4 + w;
  if (rt >= NN / 16) return;
  int r = l & 15, g = l >> 4;
  int ko = g * 8;
  f32x4 acc[8];
#pragma unroll
  for (int ct = 0; ct < 8; ++ct) acc[ct] = (f32x4){0.f, 0.f, 0.f, 0.f};

#pragma unroll
  for (int kk = 0; kk < FD; kk += 32) {
    float a0[8];
    if constexpr (F32IN != 0) {
      const float* p0 = (const float*)in + (size_t)(rt * 16 + r) * FD + kk + ko;
      float4 x0 = *(const float4*)p0;
      float4 x1 = *(const float4*)(p0 + 4);
      a0[0] = x0.x; a0[1] = x0.y; a0[2] = x0.z; a0[3] = x0.w;
      a0[4] = x1.x; a0[5] = x1.y; a0[6] = x1.z; a0[7] = x1.w;
    } else {
      uint4 pv = *(const uint4*)((const unsigned short*)in + (size_t)(rt * 16 + r) * FD + kk + ko);
      a0[0] = __uint_as_float(pv.x << 16); a0[1] = __uint_as_float(pv.x & 0xffff0000u);
      a0[2] = __uint_as_float(pv.y << 16); a0[3] = __uint_as_float(pv.y & 0xffff0000u);
      a0[4] = __uint_as_float(pv.z << 16); a0[5] = __uint_as_float(pv.z & 0xffff0000u);
      a0[6] = __uint_as_float(pv.w << 16); a0[7] = __uint_as_float(pv.w & 0xffff0000u);
    }
    if constexpr (BN != 0) {
      const float* mp = s_musc + kk + ko;
      float4 m0 = *(const float4*)mp, m1 = *(const float4*)(mp + 4);
      float4 s0 = *(const float4*)(mp + FD), s1 = *(const float4*)(mp + FD + 4);
      float mu[8] = {m0.x, m0.y, m0.z, m0.w, m1.x, m1.y, m1.z, m1.w};
      float sc[8] = {s0.x, s0.y, s0.z, s0.w, s1.x, s1.y, s1.z, s1.w};
#pragma unroll
      for (int i = 0; i < 8; ++i)
        a0[i] = fmaxf((a0[i] - mu[i]) * sc[i], 0.f);
    }
    bf16x8 ah, al;
#pragma unroll
    for (int i = 0; i < 8; ++i) {
      __bf16 h0 = (__bf16)a0[i];
      ah[i] = h0; al[i] = (__bf16)(a0[i] - (float)h0);
    }
#pragma unroll
    for (int ct = 0; ct < 8; ++ct) {
      int row = ct * 16 + r;
      int idx = row * FD + ((kk + ko) ^ ((r & 7) << 3));
      bf16x8 bh = *(const bf16x8*)(w_lds + idx);
      acc[ct] = __builtin_amdgcn_mfma_f32_16x16x32_bf16(ah, bh, acc[ct], 0, 0, 0);
      acc[ct] = __builtin_amdgcn_mfma_f32_16x16x32_bf16(al, bh, acc[ct], 0, 0, 0);
    }
  }
  float dvr[4];
#pragma unroll
  for (int i = 0; i < 4; ++i) dvr[i] = dinv[rt * 16 + g * 4 + i];
#pragma unroll
  for (int ct = 0; ct < 8; ++ct)
#pragma unroll
    for (int i = 0; i < 4; ++i)
      hb[(size_t)(rt * 16 + g * 4 + i) * FD + ct * 16 + r] = f2bf(dvr[i] * acc[ct][i]);
}

// ---------------- aggregation: XCD-aligned blocks; unweighted sum of hb' rows ----------------
// block b: XCD group g=b&7 handles nodes g*6250 + (b>>3)*16 + slot (mirrors fill partition)
#define AGG_CHUNKS 391    // ceil(6250/16)
#define GRID_AGG (8 * AGG_CHUNKS)
template <int STATS>
__global__ __launch_bounds__(256) void k_agg(const unsigned short* __restrict__ hb,
                                             const float* __restrict__ dinv,
                                             const float* __restrict__ bias, const int* __restrict__ row_off,
                                             const int* __restrict__ csr_src, unsigned short* __restrict__ outb,
                                             float* __restrict__ bn8) {
  int t = threadIdx.x;
  int b = blockIdx.x;
  int local = (b >> 3) * 16 + (t >> 4);
  bool alive = local < DRANGE;
  int n = (b & 7) * DRANGE + local;
  int q = t & 15;
  const uint4* hb4 = (const uint4*)hb;
  float4 acc0 = make_float4(0.f, 0.f, 0.f, 0.f), acc1 = make_float4(0.f, 0.f, 0.f, 0.f);
  float4 o0 = acc0, o1 = acc1;
  if (alive) {
    {
      uint4 pv = hb4[(size_t)n * 16 + q];    // self-loop term hb'[n]
      acc0.x = __uint_as_float(pv.x << 16); acc0.y = __uint_as_float(pv.x & 0xffff0000u);
      acc0.z = __uint_as_float(pv.y << 16); acc0.w = __uint_as_float(pv.y & 0xffff0000u);
      acc1.x = __uint_as_float(pv.z << 16); acc1.y = __uint_as_float(pv.z & 0xffff0000u);
      acc1.z = __uint_as_float(pv.w << 16); acc1.w = __uint_as_float(pv.w & 0xffff0000u);
    }
    int lo = row_off[n], hi = row_off[n + 1];
    for (int j = lo; j < hi; ++j) {
      int s = csr_src[j];
      uint4 pv = hb4[(size_t)s * 16 + q];
      acc0.x += __uint_as_float(pv.x << 16); acc0.y += __uint_as_float(pv.x & 0xffff0000u);
      acc0.z += __uint_as_float(pv.y << 16); acc0.w += __uint_as_float(pv.y & 0xffff0000u);
      acc1.x += __uint_as_float(pv.z << 16); acc1.y += __uint_as_float(pv.z & 0xffff0000u);
      acc1.z += __uint_as_float(pv.w << 16); acc1.w += __uint_as_float(pv.w & 0xffff0000u);
    }
    float dv = dinv[n];
    float4 b0 = ((const float4*)bias)[q * 2];
    float4 b1v = ((const float4*)bias)[q * 2 + 1];
    o0.x = fmaf(dv, acc0.x, b0.x); o0.y = fmaf(dv, acc0.y, b0.y);
    o0.z = fmaf(dv, acc0.z, b0.z); o0.w = fmaf(dv, acc0.w, b0.w);
    o1.x = fmaf(dv, acc1.x, b1v.x); o1.y = fmaf(dv, acc1.y, b1v.y);
    o1.z = fmaf(dv, acc1.z, b1v.z); o1.w = fmaf(dv, acc1.w, b1v.w);
    unsigned short o[8];
    o[0] = f2bf(o0.x); o[1] = f2bf(o0.y); o[2] = f2bf(o0.z); o[3] = f2bf(o0.w);
    o[4] = f2bf(o1.x); o[5] = f2bf(o1.y); o[6] = f2bf(o1.z); o[7] = f2bf(o1.w);
    *(uint4*)(outb + (size_t)n * FD + q * 8) = *(uint4*)o;
  }

  if constexpr (STATS != 0) {
    __shared__ float red_s[16][FD + 4], red_q[16][FD + 4];
    int slot = t >> 4, f = q * 8;
    red_s[slot][f + 0] = o0.x; red_s[slot][f + 1] = o0.y;
    red_s[slot][f + 2] = o0.z; red_s[slot][f + 3] = o0.w;
    red_s[slot][f + 4] = o1.x; red_s[slot][f + 5] = o1.y;
    red_s[slot][f + 6] = o1.z; red_s[slot][f + 7] = o1.w;
    red_q[slot][f + 0] = o0.x * o0.x; red_q[slot][f + 1] = o0.y * o0.y;
    red_q[slot][f + 2] = o0.z * o0.z; red_q[slot][f + 3] = o0.w * o0.w;
    red_q[slot][f + 4] = o1.x * o1.x; red_q[slot][f + 5] = o1.y * o1.y;
    red_q[slot][f + 6] = o1.z * o1.z; red_q[slot][f + 7] = o1.w * o1.w;
    __syncthreads();
    if (t < FD) {
      float s = 0.f, qq = 0.f;
#pragma unroll
      for (int m = 0; m < 16; ++m) { s += red_s[m][t]; qq += red_q[m][t]; }
      int c = (blockIdx.x & 7) * FD + t;
      unsafeAtomicAdd(&bn8[c], s);
      unsafeAtomicAdd(&bn8[1024 + c], qq);
    }
  }
}

// ---------------- fused pool/head (bf16 input) ----------------
__global__ __launch_bounds__(512) void k_poolfinal(const unsigned short* __restrict__ hbB,
                                                   const int* __restrict__ gstart,
                                                   const float* __restrict__ Wlin, const float* __restrict__ blin,
                                                   float* __restrict__ out) {
  __shared__ float ps[4][FD];
  __shared__ float pp[FD];
  int g = blockIdx.x, t = threadIdx.x;
  int part = t >> 7, f = t & 127;
  int lo = gstart[g], hi = gstart[g + 1];
  float s = 0.f;
  for (int n = lo + part; n < hi; n += 4) s += bf2f(hbB[(size_t)n * FD + f]);
  ps[part][f] = s;
  __syncthreads();
  if (t < FD) {
    float tot = ps[0][t] + ps[1][t] + ps[2][t] + ps[3][t];
    pp[t] = tot * (1.0f / fmaxf((float)(hi - lo), 1.0f));
  }
  __syncthreads();
  if (t < NC) {
    float a = blin[t];
    for (int k = 0; k < FD; ++k) a = fmaf(pp[k], Wlin[t * FD + k], a);
    out[g * NC + t] = a;
  }
}

// ---------------- launch ----------------
extern "C" void kernel_launch(void* const* d_in, const int* in_sizes, int n_in,
                              void* d_out, int out_size, void* d_ws, size_t ws_size,
                              hipStream_t stream) {
  const float* x    = (const float*)d_in[0];
  const int*   ei   = (const int*)d_in[1];
  const int*   batch= (const int*)d_in[2];
  const float* W1   = (const float*)d_in[3];
  const float* b1   = (const float*)d_in[4];
  const float* W2   = (const float*)d_in[5];
  const float* b2   = (const float*)d_in[6];
  const float* W3   = (const float*)d_in[7];
  const float* b3   = (const float*)d_in[8];
  const float* Wlin = (const float*)d_in[9];
  const float* blin = (const float*)d_in[10];
  float* out = (float*)d_out;
  float* ws  = (float*)d_ws;

  const int* srcI = ei;
  const int* dstI = ei + NE;

  float* deg    = ws;                       // 50048; count then dinv
  float* bnA    = ws + 50048;               // 2048 (sum8 | sq8)
  float* bnB    = bnA + 2048;               // 2048
  int*   csr_src= (int*)(bnB + 2048);       // NE
  int*   row_off= csr_src + NE;             // 50048
  int*   cursor = row_off + 50048;          // 50048
  int*   gstart = cursor + 50048;           // 1024
  int*   bsum   = gstart + 1024;            // 256
  unsigned short* w2  = (unsigned short*)(bsum + 256);   // 3*16384, pre-swizzled hi
  unsigned short* hb  = w2 + 3 * FD * FD;   // NN*FD bf16 gemm output (dinv-scaled)
  unsigned short* hbB = hb + NN * FD;       // NN*FD bf16 agg output

  dim3 B(256);
  const int gGemm = (NN / 16 + 3) / 4;   // 782 blocks, 1 rt/wave

  k_zero<<<53, B, 0, stream>>>((float4*)ws);
  k_deg_scatter<<<GRID_E8, B, 0, stream>>>(dstI, deg);
  k_bsum<<<NB, B, 0, stream>>>(deg, bsum);
  k_rowoff_cvt<<<NB + 48 + 3, B, 0, stream>>>(deg, bsum, row_off, cursor,
                                              W1, W2, W3, w2, batch, gstart);
  k_fill<<<GRID_E8, B, 0, stream>>>(srcI, dstI, cursor, csr_src);

  // layer 1 (fp32 x input)
  k_gemm<0, 1><<<gGemm, B, 0, stream>>>(x, nullptr, w2, deg, hb);
  k_agg<1><<<GRID_AGG, B, 0, stream>>>(hb, deg, b1, row_off, csr_src, hbB, bnA);

  // layer 2 (bf16 A input; BN+ReLU+musc-reduce fused into GEMM)
  k_gemm<1, 0><<<gGemm, B, 0, stream>>>(hbB, bnA, w2 + FD * FD, deg, hb);
  k_agg<1><<<GRID_AGG, B, 0, stream>>>(hb, deg, b2, row_off, csr_src, hbB, bnB);

  // layer 3
  k_gemm<1, 0><<<gGemm, B, 0, stream>>>(hbB, bnB, w2 + 2 * FD * FD, deg, hb);
  k_agg<0><<<GRID_AGG, B, 0, stream>>>(hb, deg, b3, row_off, csr_src, hbB, nullptr);

  // pool + head
  k_poolfinal<<<NG, 512, 0, stream>>>(hbB, gstart, Wlin, blin, out);
}